// Round 12
// baseline (286.920 us; speedup 1.0000x reference)
//
#include <hip/hip_runtime.h>
#include <hip/hip_fp16.h>
#include <math.h>

#define HH 512
#define WW 512
#define NIMG 8
#define NPIX (NIMG * HH * WW)          // 2,097,152
#define GAMMA_FLOW 0.001f
#define GAMMA_MASK 0.0005f
#define INV_TOTAL (1.0f / (float)(NPIX * 3))

#define HALF_PIX    (NPIX / 2)
#define LDS2_BLOCKS (HALF_PIX / 128)   // 8192 (images 0-3, 128 px/block)
#define VMEM_BLOCKS (HALF_PIX / 128)   // 8192 (images 4-7)
#define ROW_F4      (130 * 8)          // 1040 float4s per staged row

__device__ __forceinline__ float tanh_fast(float x)
{
    float e = __expf(2.0f * x);
    return 1.0f - 2.0f / (e + 1.0f);
}

__device__ __forceinline__ void fma12(float acc[3], const float wf[12],
                                      float4 x)
{
    float xv[4] = {x.x, x.y, x.z, x.w};
#pragma unroll
    for (int k = 0; k < 4; ++k) {
        acc[0] = fmaf(xv[k], wf[k * 3 + 0], acc[0]);
        acc[1] = fmaf(xv[k], wf[k * 3 + 1], acc[1]);
        acc[2] = fmaf(xv[k], wf[k * 3 + 2], acc[2]);
    }
}

// ================= K0: frames fp32 NHWC(6) -> two planar fp16 (padded 4/px) ==
__global__ __launch_bounds__(256) void cvt_kernel(
    const float* __restrict__ frames,
    __half* __restrict__ f0h, __half* __restrict__ f1h,
    float* __restrict__ tv_out)
{
    int t = blockIdx.x * 256 + threadIdx.x;            // one pixel
    if (t == 0) tv_out[0] = 0.0f;
    const float2* fp = reinterpret_cast<const float2*>(frames + (size_t)t * 6);
    float2 v0 = fp[0], v1 = fp[1], v2 = fp[2];
    __half2 a = __floats2half2_rn(v0.x, v0.y);
    __half2 b = __floats2half2_rn(v1.x, 0.0f);
    __half2 c = __floats2half2_rn(v1.y, v2.x);
    __half2 d = __floats2half2_rn(v2.y, 0.0f);
    __half2* p0 = reinterpret_cast<__half2*>(f0h) + (size_t)t * 2;
    __half2* p1 = reinterpret_cast<__half2*>(f1h) + (size_t)t * 2;
    p0[0] = a; p0[1] = b;
    p1[0] = c; p1[1] = d;
}

// ================= K1a: LDS conv v2, 4 adjacent px/thread (images 0-3) ======
// r11 lesson: LDS version was ds_read-pipe-bound (18 b128/thread for 2 px =
// 9/px x 12cyc). Sliding-window reuse: 4 adjacent px share cols -> 18 b128
// per 4 px (4.5/px) -> pipe floor ~46us/half. Block = 128 px, slab 48.8KB.
__global__ __launch_bounds__(256, 3) void conv_lds2_kernel(
    const float* __restrict__ enc, const float* __restrict__ cw,
    const float* __restrict__ cb, float* __restrict__ flow,
    float* __restrict__ mask)
{
    __shared__ float4 smem4[3 * ROW_F4];                  // [3][130][8]

    int bid = blockIdx.x;                                 // 8192 blocks
    int wb  = (bid & 7) * (LDS2_BLOCKS / 8) + (bid >> 3); // XCD swizzle
    int px0 = wb * 128;
    int n  = px0 >> 18;
    int h  = (px0 >> 9) & (HH - 1);
    int w0 = px0 & (WW - 1);                              // 0/128/256/384

    int tid = threadIdx.x;

    // ---- stage 3 rows x 130 px x 8 c4 (coalesced, zero-filled halo) ----
    const float* imgbase = enc + ((size_t)n * HH) * (WW * 32);
#pragma unroll
    for (int r = 0; r < 3; ++r) {
        int row = h + r - 1;
        bool rok = (unsigned)row < (unsigned)HH;
        const float* rowp = imgbase + (size_t)row * (WW * 32);
        for (int f = tid; f < ROW_F4; f += 256) {
            int col = f >> 3;                             // 0..129
            int c4s = f & 7;
            int gpx = w0 + col - 1;
            float4 v = make_float4(0.f, 0.f, 0.f, 0.f);
            if (rok && (unsigned)gpx < (unsigned)WW)
                v = *reinterpret_cast<const float4*>(
                        rowp + (size_t)gpx * 32 + c4s * 4);
            smem4[r * ROW_F4 + f] = v;
        }
    }
    __syncthreads();

    // ---- compute: 4 adjacent px/thread ----
    int c4   = tid & 7;
    int px0l = (tid >> 3) * 4;                            // 0,4,..,124

    const float4* cwB = reinterpret_cast<const float4*>(cw) + c4 * 3;

    float acc[4][3];
#pragma unroll
    for (int p = 0; p < 4; ++p)
        acc[p][0] = acc[p][1] = acc[p][2] = 0.0f;

#pragma unroll
    for (int kh = 0; kh < 3; ++kh) {
        float4 c6[6];                                     // cols px0l..px0l+5
#pragma unroll
        for (int j = 0; j < 6; ++j)
            c6[j] = smem4[kh * ROW_F4 + (px0l + j) * 8 + c4];
#pragma unroll
        for (int kw = 0; kw < 3; ++kw) {
            int t = kh * 3 + kw;
            float wf[12];
            *reinterpret_cast<float4*>(&wf[0]) = cwB[t * 24 + 0];
            *reinterpret_cast<float4*>(&wf[4]) = cwB[t * 24 + 1];
            *reinterpret_cast<float4*>(&wf[8]) = cwB[t * 24 + 2];
#pragma unroll
            for (int p = 0; p < 4; ++p)
                fma12(acc[p], wf, c6[p + kw]);
        }
    }

    float b0 = cb[0], b1 = cb[1], b2 = cb[2];
#pragma unroll
    for (int p = 0; p < 4; ++p) {
#pragma unroll
        for (int off = 1; off < 8; off <<= 1) {           // reduce over c4
            acc[p][0] += __shfl_xor(acc[p][0], off);
            acc[p][1] += __shfl_xor(acc[p][1], off);
            acc[p][2] += __shfl_xor(acc[p][2], off);
        }
    }
    if (c4 == 0) {
        size_t rowidx = ((size_t)n * HH + h) * WW;
#pragma unroll
        for (int p = 0; p < 4; ++p) {
            size_t idx = rowidx + (size_t)(w0 + px0l + p);
            *reinterpret_cast<float2*>(flow + idx * 2) =
                make_float2(tanh_fast(acc[p][0] + b0),
                            tanh_fast(acc[p][1] + b1));
            mask[idx] = tanh_fast(acc[p][2] + b2);
        }
    }
}

// ================= K1b: VMEM conv control (images 4-7), r6-proven ===========
__global__ __launch_bounds__(256, 4) void conv_b_kernel(
    const float* __restrict__ enc, const float* __restrict__ cw,
    const float* __restrict__ cb, float* __restrict__ flow,
    float* __restrict__ mask)
{
    int bid = blockIdx.x;                                 // 8192 blocks
    int wb  = (bid & 7) * (VMEM_BLOCKS / 8) + (bid >> 3); // XCD swizzle
    int px0 = HALF_PIX + wb * 128;
    int n = px0 >> 18;
    int h = (px0 >> 9) & (HH - 1);

    int tid  = threadIdx.x;
    int wv   = tid >> 6;
    int lane = tid & 63;
    int p3   = lane >> 3;
    int c4   = lane & 7;

    int wbase = (px0 & (WW - 1)) + wv * 32;

    const float4* cwB = reinterpret_cast<const float4*>(cw) + c4 * 3;
    const float* imgbase = enc + ((size_t)n * HH) * (WW * 32);

    float acc[4][3];
#pragma unroll
    for (int pg = 0; pg < 4; ++pg)
        acc[pg][0] = acc[pg][1] = acc[pg][2] = 0.0f;

    bool edge = (wbase == 0) || (wbase == WW - 32);

    if (!edge) {
#pragma unroll
        for (int kh = 0; kh < 3; ++kh) {
            int hr = h + kh - 1;
            if ((unsigned)hr >= (unsigned)HH) continue;
            const float* pB = imgbase + (size_t)hr * (WW * 32)
                            + (wbase - 1 + p3) * 32 + c4 * 4;
#pragma unroll
            for (int kw = 0; kw < 3; ++kw) {
                int t = kh * 3 + kw;
                float wf[12];
                *reinterpret_cast<float4*>(&wf[0]) = cwB[t * 24 + 0];
                *reinterpret_cast<float4*>(&wf[4]) = cwB[t * 24 + 1];
                *reinterpret_cast<float4*>(&wf[8]) = cwB[t * 24 + 2];
#pragma unroll
                for (int pg = 0; pg < 4; ++pg) {
                    float4 x = *reinterpret_cast<const float4*>(
                                   pB + (pg * 8 + kw) * 32);
                    fma12(acc[pg], wf, x);
                }
            }
        }
    } else {
#pragma unroll
        for (int kh = 0; kh < 3; ++kh) {
            int hr = h + kh - 1;
            if ((unsigned)hr >= (unsigned)HH) continue;
            const float* rowp = imgbase + (size_t)hr * (WW * 32);
#pragma unroll
            for (int kw = 0; kw < 3; ++kw) {
                int t = kh * 3 + kw;
                float wf[12];
                *reinterpret_cast<float4*>(&wf[0]) = cwB[t * 24 + 0];
                *reinterpret_cast<float4*>(&wf[4]) = cwB[t * 24 + 1];
                *reinterpret_cast<float4*>(&wf[8]) = cwB[t * 24 + 2];
#pragma unroll
                for (int pg = 0; pg < 4; ++pg) {
                    int wc = wbase + p3 + pg * 8 + kw - 1;
                    float4 x = make_float4(0.f, 0.f, 0.f, 0.f);
                    if ((unsigned)wc < (unsigned)WW)
                        x = *reinterpret_cast<const float4*>(
                                rowp + wc * 32 + c4 * 4);
                    fma12(acc[pg], wf, x);
                }
            }
        }
    }

    float b0 = cb[0], b1 = cb[1], b2 = cb[2];
    size_t rowidx = ((size_t)n * HH + h) * WW;

#pragma unroll
    for (int pg = 0; pg < 4; ++pg) {
        float a0 = acc[pg][0], a1 = acc[pg][1], a2 = acc[pg][2];
#pragma unroll
        for (int off = 1; off < 8; off <<= 1) {
            a0 += __shfl_xor(a0, off);
            a1 += __shfl_xor(a1, off);
            a2 += __shfl_xor(a2, off);
        }
        float t0 = tanh_fast(a0 + b0);
        float t1 = tanh_fast(a1 + b1);
        float t2 = tanh_fast(a2 + b2);
        if (c4 == 0) {
            size_t idx = rowidx + (size_t)(wbase + p3 + pg * 8);
            *reinterpret_cast<float2*>(flow + idx * 2) = make_float2(t0, t1);
            mask[idx] = t2;
        }
    }
}

// ================= K2: bilinear warp + blend + TV (unchanged, ~47us) ========
__device__ __forceinline__ void bilerp_h(const __half* __restrict__ img,
                                         float ch, float cwv, float out[3])
{
    float hp = (ch + 1.0f) * 255.5f;
    float wp = (cwv + 1.0f) * 255.5f;
    int h0 = (int)floorf(hp);
    int w0 = (int)floorf(wp);
    int h1  = min(max(h0 + 1, 0), HH - 1);
    int w1  = min(max(w0 + 1, 0), WW - 1);
    int h0c = min(max(h0, 0), HH - 1);
    int w0c = min(max(w0, 0), WW - 1);
    float wh = (float)h1 - hp;
    float wv = (float)w1 - wp;
    float w_ru = wh * wv;
    float w_rd = (1.0f - wh) * wv;
    float w_lu = wh * (1.0f - wv);
    float w_ld = (1.0f - wh) * (1.0f - wv);

    int q = min(w0c, WW - 2);
    bool Ahi = (w0c != q);
    bool Bhi = (w1 == q + 1);
    float4 U = *reinterpret_cast<const float4*>(img + (size_t)(((h0c << 9) + q) << 2));
    float4 D = *reinterpret_cast<const float4*>(img + (size_t)(((h1  << 9) + q) << 2));
    float ru_ab = Ahi ? U.z : U.x, ru_c = Ahi ? U.w : U.y;
    float rd_ab = Ahi ? D.z : D.x, rd_c = Ahi ? D.w : D.y;
    float lu_ab = Bhi ? U.z : U.x, lu_c = Bhi ? U.w : U.y;
    float ld_ab = Bhi ? D.z : D.x, ld_c = Bhi ? D.w : D.y;

    float2 ruA = __half22float2(*reinterpret_cast<__half2*>(&ru_ab));
    float2 rdA = __half22float2(*reinterpret_cast<__half2*>(&rd_ab));
    float2 luA = __half22float2(*reinterpret_cast<__half2*>(&lu_ab));
    float2 ldA = __half22float2(*reinterpret_cast<__half2*>(&ld_ab));
    float ruZ = __half2float(reinterpret_cast<__half2*>(&ru_c)->x);
    float rdZ = __half2float(reinterpret_cast<__half2*>(&rd_c)->x);
    float luZ = __half2float(reinterpret_cast<__half2*>(&lu_c)->x);
    float ldZ = __half2float(reinterpret_cast<__half2*>(&ld_c)->x);

    out[0] = w_ru * ruA.x + w_rd * rdA.x + w_lu * luA.x + w_ld * ldA.x;
    out[1] = w_ru * ruA.y + w_rd * rdA.y + w_lu * luA.y + w_ld * ldA.y;
    out[2] = w_ru * ruZ   + w_rd * rdZ   + w_lu * luZ   + w_ld * ldZ;
}

__global__ __launch_bounds__(256, 4) void interp_tv_kernel(
    const __half* __restrict__ f0h, const __half* __restrict__ f1h,
    const float* __restrict__ flow, const float* __restrict__ mask,
    float* __restrict__ stacked, float* __restrict__ tv_out)
{
    int bid = blockIdx.x;                                  // 1024 blocks
    int wb  = (bid & 7) * (NPIX / 2048 / 8) + (bid >> 3);  // image n -> XCD n
    int idx0 = wb * 2048 + (int)threadIdx.x * 8;           // 8 adjacent px
    int w0 = idx0 & (WW - 1);
    int h  = (idx0 >> 9) & (HH - 1);
    int n  = idx0 >> 18;

    float4 fl[4];
#pragma unroll
    for (int j = 0; j < 4; ++j)
        fl[j] = *reinterpret_cast<const float4*>(flow + (size_t)idx0 * 2 + j * 4);
    float4 mkA = *reinterpret_cast<const float4*>(mask + idx0);
    float4 mkB = *reinterpret_cast<const float4*>(mask + idx0 + 4);
    const float* flp = reinterpret_cast<const float*>(fl);
    float mkp[8] = {mkA.x, mkA.y, mkA.z, mkA.w, mkB.x, mkB.y, mkB.z, mkB.w};

    float hhv = -1.0f + (float)h * (2.0f / 511.0f);

    const __half* i0 = f0h + (size_t)n * (HH * WW * 4);
    const __half* i1 = f1h + (size_t)n * (HH * WW * 4);

    float res[24];
#pragma unroll
    for (int p = 0; p < 8; ++p) {
        float wvx = -1.0f + (float)(w0 + p) * (2.0f / 511.0f);
        float fx = flp[p * 2], fy = flp[p * 2 + 1];
        float o0[3], o1[3];
        bilerp_h(i0, hhv + fx * 0.5f, wvx + fy * 0.5f, o0);
        bilerp_h(i1, hhv - fx * 0.5f, wvx - fy * 0.5f, o1);
        float m = 0.5f * (1.0f + mkp[p]), om = 1.0f - m;
#pragma unroll
        for (int c = 0; c < 3; ++c)
            res[p * 3 + c] = m * o0[c] + om * o1[c];
    }
    float4* sp = reinterpret_cast<float4*>(stacked + (size_t)idx0 * 3);
#pragma unroll
    for (int j = 0; j < 6; ++j)
        sp[j] = make_float4(res[j * 4], res[j * 4 + 1],
                            res[j * 4 + 2], res[j * 4 + 3]);

    float tvf = 0.0f, tvm = 0.0f;
#pragma unroll
    for (int p = 0; p < 7; ++p) {
        tvf += fabsf(flp[p * 2 + 2] - flp[p * 2])
             + fabsf(flp[p * 2 + 3] - flp[p * 2 + 1]);
        tvm += fabsf(mkp[p + 1] - mkp[p]);
    }
    if (w0 < WW - 8) {
        float2 flr = *reinterpret_cast<const float2*>(flow + (size_t)(idx0 + 8) * 2);
        float  mkr = mask[idx0 + 8];
        tvf += fabsf(flr.x - flp[14]) + fabsf(flr.y - flp[15]);
        tvm += fabsf(mkr - mkp[7]);
    }
    if (h < HH - 1) {
#pragma unroll
        for (int j = 0; j < 4; ++j) {
            float4 fd = *reinterpret_cast<const float4*>(
                            flow + (size_t)(idx0 + WW) * 2 + j * 4);
            tvf += fabsf(fd.x - flp[j * 4 + 0]) + fabsf(fd.y - flp[j * 4 + 1])
                 + fabsf(fd.z - flp[j * 4 + 2]) + fabsf(fd.w - flp[j * 4 + 3]);
        }
        float4 mdA = *reinterpret_cast<const float4*>(mask + idx0 + WW);
        float4 mdB = *reinterpret_cast<const float4*>(mask + idx0 + WW + 4);
        tvm += fabsf(mdA.x - mkp[0]) + fabsf(mdA.y - mkp[1])
             + fabsf(mdA.z - mkp[2]) + fabsf(mdA.w - mkp[3])
             + fabsf(mdB.x - mkp[4]) + fabsf(mdB.y - mkp[5])
             + fabsf(mdB.z - mkp[6]) + fabsf(mdB.w - mkp[7]);
    }
    float tv = GAMMA_FLOW * tvf + GAMMA_MASK * tvm;
#pragma unroll
    for (int off = 32; off > 0; off >>= 1) tv += __shfl_xor(tv, off);
    if ((threadIdx.x & 63) == 0) atomicAdd(tv_out, tv * INV_TOTAL);
}

extern "C" void kernel_launch(void* const* d_in, const int* in_sizes, int n_in,
                              void* d_out, int out_size, void* d_ws, size_t ws_size,
                              hipStream_t stream)
{
    const float* frames  = (const float*)d_in[0];
    const float* encoded = (const float*)d_in[1];
    const float* conv_w  = (const float*)d_in[2];
    const float* conv_b  = (const float*)d_in[3];

    float* out     = (float*)d_out;
    float* stacked = out;                       // NPIX*3
    float* flow    = out + (size_t)NPIX * 3;    // NPIX*2
    float* tv      = out + (size_t)NPIX * 5;    // 1

    const size_t frame_bytes = (size_t)NPIX * 4 * sizeof(__half); // 16 MiB each
    __half* f0h = (__half*)d_ws;
    __half* f1h = (__half*)((char*)d_ws + frame_bytes);
    float*  mask = (float*)((char*)d_ws + 2 * frame_bytes);

    cvt_kernel<<<NPIX / 256, 256, 0, stream>>>(frames, f0h, f1h, tv);
    conv_lds2_kernel<<<LDS2_BLOCKS, 256, 0, stream>>>(encoded, conv_w, conv_b,
                                                      flow, mask);
    conv_b_kernel<<<VMEM_BLOCKS, 256, 0, stream>>>(encoded, conv_w, conv_b,
                                                   flow, mask);
    interp_tv_kernel<<<NPIX / 2048, 256, 0, stream>>>(
        f0h, f1h, flow, mask, stacked, tv);
}

// Round 13
// 285.087 us; speedup vs baseline: 1.0064x; 1.0064x over previous
//
#include <hip/hip_runtime.h>
#include <hip/hip_fp16.h>
#include <math.h>

#define HH 512
#define WW 512
#define NIMG 8
#define NPIX (NIMG * HH * WW)          // 2,097,152
#define GAMMA_FLOW 0.001f
#define GAMMA_MASK 0.0005f
#define INV_TOTAL (1.0f / (float)(NPIX * 3))

#define HALF_PIX    (NPIX / 2)
#define HALF_BLOCKS (HALF_PIX / 128)   // 8192 conv blocks per 4-image half

__device__ __forceinline__ float tanh_fast(float x)
{
    float e = __expf(2.0f * x);
    return 1.0f - 2.0f / (e + 1.0f);
}

__device__ __forceinline__ void fma12(float acc[3], const float wf[12],
                                      float4 x)
{
    float xv[4] = {x.x, x.y, x.z, x.w};
#pragma unroll
    for (int k = 0; k < 4; ++k) {
        acc[0] = fmaf(xv[k], wf[k * 3 + 0], acc[0]);
        acc[1] = fmaf(xv[k], wf[k * 3 + 1], acc[1]);
        acc[2] = fmaf(xv[k], wf[k * 3 + 2], acc[2]);
    }
}

// ================= K0: frames fp32 NHWC(6) -> two planar fp16 (padded 4/px) ==
__global__ __launch_bounds__(256) void cvt_kernel(
    const float* __restrict__ frames,
    __half* __restrict__ f0h, __half* __restrict__ f1h,
    float* __restrict__ tv_out)
{
    int t = blockIdx.x * 256 + threadIdx.x;            // one pixel
    if (t == 0) tv_out[0] = 0.0f;
    const float2* fp = reinterpret_cast<const float2*>(frames + (size_t)t * 6);
    float2 v0 = fp[0], v1 = fp[1], v2 = fp[2];
    __half2 a = __floats2half2_rn(v0.x, v0.y);
    __half2 b = __floats2half2_rn(v1.x, 0.0f);
    __half2 c = __floats2half2_rn(v1.y, v2.x);
    __half2 d = __floats2half2_rn(v2.y, 0.0f);
    __half2* p0 = reinterpret_cast<__half2*>(f0h) + (size_t)t * 2;
    __half2* p1 = reinterpret_cast<__half2*>(f1h) + (size_t)t * 2;
    p0[0] = a; p0[1] = b;
    p1[0] = c; p1[1] = d;
}

// ================= K1: 3x3x32->3 conv + tanh (r6 VMEM structure) =============
// Mechanism model (r6-r12): launch_bounds(256,N) emits waves-per-eu=[N,N] ->
// budget 256/N AND HW residency cap N. All conv variants stuck at 3-4 w/EU.
// conv_a tests amdgpu_waves_per_eu(4,8): budget from min (64 regs, proven
// fit) while allowing 8 resident waves/EU. conv_b = (256,4) control.
__device__ __forceinline__ void conv_body(
    const float* __restrict__ enc, const float* __restrict__ cw,
    const float* __restrict__ cb, float* __restrict__ flow,
    float* __restrict__ mask, int px_base)
{
    int bid = blockIdx.x;                                 // 8192 blocks
    int wb  = (bid & 7) * (HALF_BLOCKS / 8) + (bid >> 3); // XCD swizzle
    int px0 = px_base + wb * 128;
    int n = px0 >> 18;
    int h = (px0 >> 9) & (HH - 1);

    int tid  = threadIdx.x;
    int wv   = tid >> 6;
    int lane = tid & 63;
    int p3   = lane >> 3;                                 // pixel in group
    int c4   = lane & 7;                                  // channel chunk

    int wbase = (px0 & (WW - 1)) + wv * 32;               // wave's 32-px seg

    const float4* cwB = reinterpret_cast<const float4*>(cw) + c4 * 3;
    const float* imgbase = enc + ((size_t)n * HH) * (WW * 32);

    float acc[4][3];
#pragma unroll
    for (int pg = 0; pg < 4; ++pg)
        acc[pg][0] = acc[pg][1] = acc[pg][2] = 0.0f;

    bool edge = (wbase == 0) || (wbase == WW - 32);       // wave-uniform

    if (!edge) {
#pragma unroll
        for (int kh = 0; kh < 3; ++kh) {
            int hr = h + kh - 1;
            if ((unsigned)hr >= (unsigned)HH) continue;   // block-uniform
            const float* pB = imgbase + (size_t)hr * (WW * 32)
                            + (wbase - 1 + p3) * 32 + c4 * 4;
#pragma unroll
            for (int kw = 0; kw < 3; ++kw) {
                int t = kh * 3 + kw;
                float wf[12];
                *reinterpret_cast<float4*>(&wf[0]) = cwB[t * 24 + 0];
                *reinterpret_cast<float4*>(&wf[4]) = cwB[t * 24 + 1];
                *reinterpret_cast<float4*>(&wf[8]) = cwB[t * 24 + 2];
#pragma unroll
                for (int pg = 0; pg < 4; ++pg) {
                    float4 x = *reinterpret_cast<const float4*>(
                                   pB + (pg * 8 + kw) * 32);
                    fma12(acc[pg], wf, x);
                }
            }
        }
    } else {
#pragma unroll
        for (int kh = 0; kh < 3; ++kh) {
            int hr = h + kh - 1;
            if ((unsigned)hr >= (unsigned)HH) continue;
            const float* rowp = imgbase + (size_t)hr * (WW * 32);
#pragma unroll
            for (int kw = 0; kw < 3; ++kw) {
                int t = kh * 3 + kw;
                float wf[12];
                *reinterpret_cast<float4*>(&wf[0]) = cwB[t * 24 + 0];
                *reinterpret_cast<float4*>(&wf[4]) = cwB[t * 24 + 1];
                *reinterpret_cast<float4*>(&wf[8]) = cwB[t * 24 + 2];
#pragma unroll
                for (int pg = 0; pg < 4; ++pg) {
                    int wc = wbase + p3 + pg * 8 + kw - 1;
                    float4 x = make_float4(0.f, 0.f, 0.f, 0.f);
                    if ((unsigned)wc < (unsigned)WW)
                        x = *reinterpret_cast<const float4*>(
                                rowp + wc * 32 + c4 * 4);
                    fma12(acc[pg], wf, x);
                }
            }
        }
    }

    float b0 = cb[0], b1 = cb[1], b2 = cb[2];
    size_t rowidx = ((size_t)n * HH + h) * WW;

#pragma unroll
    for (int pg = 0; pg < 4; ++pg) {
        float a0 = acc[pg][0], a1 = acc[pg][1], a2 = acc[pg][2];
#pragma unroll
        for (int off = 1; off < 8; off <<= 1) {           // reduce over c4
            a0 += __shfl_xor(a0, off);
            a1 += __shfl_xor(a1, off);
            a2 += __shfl_xor(a2, off);
        }
        float t0 = tanh_fast(a0 + b0);
        float t1 = tanh_fast(a1 + b1);
        float t2 = tanh_fast(a2 + b2);
        if (c4 == 0) {
            size_t idx = rowidx + (size_t)(wbase + p3 + pg * 8);
            *reinterpret_cast<float2*>(flow + idx * 2) = make_float2(t0, t1);
            mask[idx] = t2;
        }
    }
}

// A: experimental -- budget for 4 waves/EU (64 regs), residency allowed to 8
__global__ __attribute__((amdgpu_waves_per_eu(4, 8))) __launch_bounds__(256)
void conv_a_kernel(const float* __restrict__ enc, const float* __restrict__ cw,
                   const float* __restrict__ cb, float* __restrict__ flow,
                   float* __restrict__ mask)
{
    conv_body(enc, cw, cb, flow, mask, 0);
}

// B: control -- proven (256,4), 95us/half
__global__ __launch_bounds__(256, 4)
void conv_b_kernel(const float* __restrict__ enc, const float* __restrict__ cw,
                   const float* __restrict__ cb, float* __restrict__ flow,
                   float* __restrict__ mask)
{
    conv_body(enc, cw, cb, flow, mask, HALF_PIX);
}

// ================= K2: bilinear warp + blend + TV (unchanged, ~47us) ========
__device__ __forceinline__ void bilerp_h(const __half* __restrict__ img,
                                         float ch, float cwv, float out[3])
{
    float hp = (ch + 1.0f) * 255.5f;
    float wp = (cwv + 1.0f) * 255.5f;
    int h0 = (int)floorf(hp);
    int w0 = (int)floorf(wp);
    int h1  = min(max(h0 + 1, 0), HH - 1);
    int w1  = min(max(w0 + 1, 0), WW - 1);
    int h0c = min(max(h0, 0), HH - 1);
    int w0c = min(max(w0, 0), WW - 1);
    float wh = (float)h1 - hp;
    float wv = (float)w1 - wp;
    float w_ru = wh * wv;
    float w_rd = (1.0f - wh) * wv;
    float w_lu = wh * (1.0f - wv);
    float w_ld = (1.0f - wh) * (1.0f - wv);

    int q = min(w0c, WW - 2);
    bool Ahi = (w0c != q);
    bool Bhi = (w1 == q + 1);
    float4 U = *reinterpret_cast<const float4*>(img + (size_t)(((h0c << 9) + q) << 2));
    float4 D = *reinterpret_cast<const float4*>(img + (size_t)(((h1  << 9) + q) << 2));
    float ru_ab = Ahi ? U.z : U.x, ru_c = Ahi ? U.w : U.y;
    float rd_ab = Ahi ? D.z : D.x, rd_c = Ahi ? D.w : D.y;
    float lu_ab = Bhi ? U.z : U.x, lu_c = Bhi ? U.w : U.y;
    float ld_ab = Bhi ? D.z : D.x, ld_c = Bhi ? D.w : D.y;

    float2 ruA = __half22float2(*reinterpret_cast<__half2*>(&ru_ab));
    float2 rdA = __half22float2(*reinterpret_cast<__half2*>(&rd_ab));
    float2 luA = __half22float2(*reinterpret_cast<__half2*>(&lu_ab));
    float2 ldA = __half22float2(*reinterpret_cast<__half2*>(&ld_ab));
    float ruZ = __half2float(reinterpret_cast<__half2*>(&ru_c)->x);
    float rdZ = __half2float(reinterpret_cast<__half2*>(&rd_c)->x);
    float luZ = __half2float(reinterpret_cast<__half2*>(&lu_c)->x);
    float ldZ = __half2float(reinterpret_cast<__half2*>(&ld_c)->x);

    out[0] = w_ru * ruA.x + w_rd * rdA.x + w_lu * luA.x + w_ld * ldA.x;
    out[1] = w_ru * ruA.y + w_rd * rdA.y + w_lu * luA.y + w_ld * ldA.y;
    out[2] = w_ru * ruZ   + w_rd * rdZ   + w_lu * luZ   + w_ld * ldZ;
}

__global__ __launch_bounds__(256, 4) void interp_tv_kernel(
    const __half* __restrict__ f0h, const __half* __restrict__ f1h,
    const float* __restrict__ flow, const float* __restrict__ mask,
    float* __restrict__ stacked, float* __restrict__ tv_out)
{
    int bid = blockIdx.x;                                  // 1024 blocks
    int wb  = (bid & 7) * (NPIX / 2048 / 8) + (bid >> 3);  // image n -> XCD n
    int idx0 = wb * 2048 + (int)threadIdx.x * 8;           // 8 adjacent px
    int w0 = idx0 & (WW - 1);
    int h  = (idx0 >> 9) & (HH - 1);
    int n  = idx0 >> 18;

    float4 fl[4];
#pragma unroll
    for (int j = 0; j < 4; ++j)
        fl[j] = *reinterpret_cast<const float4*>(flow + (size_t)idx0 * 2 + j * 4);
    float4 mkA = *reinterpret_cast<const float4*>(mask + idx0);
    float4 mkB = *reinterpret_cast<const float4*>(mask + idx0 + 4);
    const float* flp = reinterpret_cast<const float*>(fl);
    float mkp[8] = {mkA.x, mkA.y, mkA.z, mkA.w, mkB.x, mkB.y, mkB.z, mkB.w};

    float hhv = -1.0f + (float)h * (2.0f / 511.0f);

    const __half* i0 = f0h + (size_t)n * (HH * WW * 4);
    const __half* i1 = f1h + (size_t)n * (HH * WW * 4);

    float res[24];
#pragma unroll
    for (int p = 0; p < 8; ++p) {
        float wvx = -1.0f + (float)(w0 + p) * (2.0f / 511.0f);
        float fx = flp[p * 2], fy = flp[p * 2 + 1];
        float o0[3], o1[3];
        bilerp_h(i0, hhv + fx * 0.5f, wvx + fy * 0.5f, o0);
        bilerp_h(i1, hhv - fx * 0.5f, wvx - fy * 0.5f, o1);
        float m = 0.5f * (1.0f + mkp[p]), om = 1.0f - m;
#pragma unroll
        for (int c = 0; c < 3; ++c)
            res[p * 3 + c] = m * o0[c] + om * o1[c];
    }
    float4* sp = reinterpret_cast<float4*>(stacked + (size_t)idx0 * 3);
#pragma unroll
    for (int j = 0; j < 6; ++j)
        sp[j] = make_float4(res[j * 4], res[j * 4 + 1],
                            res[j * 4 + 2], res[j * 4 + 3]);

    float tvf = 0.0f, tvm = 0.0f;
#pragma unroll
    for (int p = 0; p < 7; ++p) {
        tvf += fabsf(flp[p * 2 + 2] - flp[p * 2])
             + fabsf(flp[p * 2 + 3] - flp[p * 2 + 1]);
        tvm += fabsf(mkp[p + 1] - mkp[p]);
    }
    if (w0 < WW - 8) {
        float2 flr = *reinterpret_cast<const float2*>(flow + (size_t)(idx0 + 8) * 2);
        float  mkr = mask[idx0 + 8];
        tvf += fabsf(flr.x - flp[14]) + fabsf(flr.y - flp[15]);
        tvm += fabsf(mkr - mkp[7]);
    }
    if (h < HH - 1) {
#pragma unroll
        for (int j = 0; j < 4; ++j) {
            float4 fd = *reinterpret_cast<const float4*>(
                            flow + (size_t)(idx0 + WW) * 2 + j * 4);
            tvf += fabsf(fd.x - flp[j * 4 + 0]) + fabsf(fd.y - flp[j * 4 + 1])
                 + fabsf(fd.z - flp[j * 4 + 2]) + fabsf(fd.w - flp[j * 4 + 3]);
        }
        float4 mdA = *reinterpret_cast<const float4*>(mask + idx0 + WW);
        float4 mdB = *reinterpret_cast<const float4*>(mask + idx0 + WW + 4);
        tvm += fabsf(mdA.x - mkp[0]) + fabsf(mdA.y - mkp[1])
             + fabsf(mdA.z - mkp[2]) + fabsf(mdA.w - mkp[3])
             + fabsf(mdB.x - mkp[4]) + fabsf(mdB.y - mkp[5])
             + fabsf(mdB.z - mkp[6]) + fabsf(mdB.w - mkp[7]);
    }
    float tv = GAMMA_FLOW * tvf + GAMMA_MASK * tvm;
#pragma unroll
    for (int off = 32; off > 0; off >>= 1) tv += __shfl_xor(tv, off);
    if ((threadIdx.x & 63) == 0) atomicAdd(tv_out, tv * INV_TOTAL);
}

extern "C" void kernel_launch(void* const* d_in, const int* in_sizes, int n_in,
                              void* d_out, int out_size, void* d_ws, size_t ws_size,
                              hipStream_t stream)
{
    const float* frames  = (const float*)d_in[0];
    const float* encoded = (const float*)d_in[1];
    const float* conv_w  = (const float*)d_in[2];
    const float* conv_b  = (const float*)d_in[3];

    float* out     = (float*)d_out;
    float* stacked = out;                       // NPIX*3
    float* flow    = out + (size_t)NPIX * 3;    // NPIX*2
    float* tv      = out + (size_t)NPIX * 5;    // 1

    const size_t frame_bytes = (size_t)NPIX * 4 * sizeof(__half); // 16 MiB each
    __half* f0h = (__half*)d_ws;
    __half* f1h = (__half*)((char*)d_ws + frame_bytes);
    float*  mask = (float*)((char*)d_ws + 2 * frame_bytes);

    cvt_kernel<<<NPIX / 256, 256, 0, stream>>>(frames, f0h, f1h, tv);
    conv_a_kernel<<<HALF_BLOCKS, 256, 0, stream>>>(encoded, conv_w, conv_b,
                                                   flow, mask);
    conv_b_kernel<<<HALF_BLOCKS, 256, 0, stream>>>(encoded, conv_w, conv_b,
                                                   flow, mask);
    interp_tv_kernel<<<NPIX / 2048, 256, 0, stream>>>(
        f0h, f1h, flow, mask, stacked, tv);
}

// Round 14
// 261.207 us; speedup vs baseline: 1.0984x; 1.0914x over previous
//
#include <hip/hip_runtime.h>
#include <hip/hip_fp16.h>
#include <math.h>

#define HH 512
#define WW 512
#define NIMG 8
#define NPIX (NIMG * HH * WW)          // 2,097,152
#define GAMMA_FLOW 0.001f
#define GAMMA_MASK 0.0005f
#define INV_TOTAL (1.0f / (float)(NPIX * 3))

#define CVT_BLOCKS  (NPIX / 256)       // 8192
#define CONV_BLOCKS (NPIX / 128)       // 16384
#define FAT_BLOCKS  (CVT_BLOCKS + CONV_BLOCKS)  // 24576

__device__ __forceinline__ float tanh_fast(float x)
{
    float e = __expf(2.0f * x);
    return 1.0f - 2.0f / (e + 1.0f);
}

__device__ __forceinline__ void fma12(float acc[3], const float wf[12],
                                      float4 x)
{
    float xv[4] = {x.x, x.y, x.z, x.w};
#pragma unroll
    for (int k = 0; k < 4; ++k) {
        acc[0] = fmaf(xv[k], wf[k * 3 + 0], acc[0]);
        acc[1] = fmaf(xv[k], wf[k * 3 + 1], acc[1]);
        acc[2] = fmaf(xv[k], wf[k * 3 + 2], acc[2]);
    }
}

// ========== K1 (fat): bid%3==0 -> cvt block ; else -> conv block ============
// Interleaving (not r7's front-back split) so cvt's BW-heavy waves fill the
// conv waves' latency gaps on every CU for the whole dispatch. (256,4) is the
// proven conv config (64-reg budget, 95us/half); r7's failure was its (256,8)
// -> 32-reg budget, not the fusion.
__global__ __launch_bounds__(256, 4) void fat_kernel(
    const float* __restrict__ enc, const float* __restrict__ cw,
    const float* __restrict__ cb, const float* __restrict__ frames,
    float* __restrict__ flow, float* __restrict__ mask,
    __half* __restrict__ f0h, __half* __restrict__ f1h,
    float* __restrict__ tv_out)
{
    int bid = blockIdx.x;

    if (bid % 3 == 0) {
        // ---------------- cvt: fp32 NHWC(6) -> two planar fp16(4) ----------
        int ci = bid / 3;                              // 0..8191
        int t  = ci * 256 + threadIdx.x;               // one pixel
        if (t == 0) tv_out[0] = 0.0f;
        const float2* fp = reinterpret_cast<const float2*>(frames + (size_t)t * 6);
        float2 v0 = fp[0], v1 = fp[1], v2 = fp[2];
        __half2 a = __floats2half2_rn(v0.x, v0.y);
        __half2 b = __floats2half2_rn(v1.x, 0.0f);
        __half2 c = __floats2half2_rn(v1.y, v2.x);
        __half2 d = __floats2half2_rn(v2.y, 0.0f);
        __half2* p0 = reinterpret_cast<__half2*>(f0h) + (size_t)t * 2;
        __half2* p1 = reinterpret_cast<__half2*>(f1h) + (size_t)t * 2;
        p0[0] = a; p0[1] = b;
        p1[0] = c; p1[1] = d;
        return;
    }

    // ---------------- conv: 3x3x32->3 + tanh (r6 body, proven) -------------
    int ci  = bid - (bid + 2) / 3;                        // 0..16383
    int wb  = (ci & 7) * (CONV_BLOCKS / 8) + (ci >> 3);   // image n -> XCD n
    int px0 = wb * 128;
    int n = px0 >> 18;
    int h = (px0 >> 9) & (HH - 1);

    int tid  = threadIdx.x;
    int wv   = tid >> 6;
    int lane = tid & 63;
    int p3   = lane >> 3;                                 // pixel in group
    int c4   = lane & 7;                                  // channel chunk

    int wbase = (px0 & (WW - 1)) + wv * 32;               // wave's 32-px seg

    const float4* cwB = reinterpret_cast<const float4*>(cw) + c4 * 3;
    const float* imgbase = enc + ((size_t)n * HH) * (WW * 32);

    float acc[4][3];
#pragma unroll
    for (int pg = 0; pg < 4; ++pg)
        acc[pg][0] = acc[pg][1] = acc[pg][2] = 0.0f;

    bool edge = (wbase == 0) || (wbase == WW - 32);       // wave-uniform

    if (!edge) {
#pragma unroll
        for (int kh = 0; kh < 3; ++kh) {
            int hr = h + kh - 1;
            if ((unsigned)hr >= (unsigned)HH) continue;   // block-uniform
            const float* pB = imgbase + (size_t)hr * (WW * 32)
                            + (wbase - 1 + p3) * 32 + c4 * 4;
#pragma unroll
            for (int kw = 0; kw < 3; ++kw) {
                int t = kh * 3 + kw;
                float wf[12];
                *reinterpret_cast<float4*>(&wf[0]) = cwB[t * 24 + 0];
                *reinterpret_cast<float4*>(&wf[4]) = cwB[t * 24 + 1];
                *reinterpret_cast<float4*>(&wf[8]) = cwB[t * 24 + 2];
#pragma unroll
                for (int pg = 0; pg < 4; ++pg) {
                    float4 x = *reinterpret_cast<const float4*>(
                                   pB + (pg * 8 + kw) * 32);
                    fma12(acc[pg], wf, x);
                }
            }
        }
    } else {
#pragma unroll
        for (int kh = 0; kh < 3; ++kh) {
            int hr = h + kh - 1;
            if ((unsigned)hr >= (unsigned)HH) continue;
            const float* rowp = imgbase + (size_t)hr * (WW * 32);
#pragma unroll
            for (int kw = 0; kw < 3; ++kw) {
                int t = kh * 3 + kw;
                float wf[12];
                *reinterpret_cast<float4*>(&wf[0]) = cwB[t * 24 + 0];
                *reinterpret_cast<float4*>(&wf[4]) = cwB[t * 24 + 1];
                *reinterpret_cast<float4*>(&wf[8]) = cwB[t * 24 + 2];
#pragma unroll
                for (int pg = 0; pg < 4; ++pg) {
                    int wc = wbase + p3 + pg * 8 + kw - 1;
                    float4 x = make_float4(0.f, 0.f, 0.f, 0.f);
                    if ((unsigned)wc < (unsigned)WW)
                        x = *reinterpret_cast<const float4*>(
                                rowp + wc * 32 + c4 * 4);
                    fma12(acc[pg], wf, x);
                }
            }
        }
    }

    float b0 = cb[0], b1 = cb[1], b2 = cb[2];
    size_t rowidx = ((size_t)n * HH + h) * WW;

#pragma unroll
    for (int pg = 0; pg < 4; ++pg) {
        float a0 = acc[pg][0], a1 = acc[pg][1], a2 = acc[pg][2];
#pragma unroll
        for (int off = 1; off < 8; off <<= 1) {           // reduce over c4
            a0 += __shfl_xor(a0, off);
            a1 += __shfl_xor(a1, off);
            a2 += __shfl_xor(a2, off);
        }
        float t0 = tanh_fast(a0 + b0);
        float t1 = tanh_fast(a1 + b1);
        float t2 = tanh_fast(a2 + b2);
        if (c4 == 0) {
            size_t idx = rowidx + (size_t)(wbase + p3 + pg * 8);
            *reinterpret_cast<float2*>(flow + idx * 2) = make_float2(t0, t1);
            mask[idx] = t2;
        }
    }
}

// ================= K2: bilinear warp + blend + TV (unchanged, ~47us) ========
__device__ __forceinline__ void bilerp_h(const __half* __restrict__ img,
                                         float ch, float cwv, float out[3])
{
    float hp = (ch + 1.0f) * 255.5f;
    float wp = (cwv + 1.0f) * 255.5f;
    int h0 = (int)floorf(hp);
    int w0 = (int)floorf(wp);
    int h1  = min(max(h0 + 1, 0), HH - 1);
    int w1  = min(max(w0 + 1, 0), WW - 1);
    int h0c = min(max(h0, 0), HH - 1);
    int w0c = min(max(w0, 0), WW - 1);
    float wh = (float)h1 - hp;
    float wv = (float)w1 - wp;
    float w_ru = wh * wv;
    float w_rd = (1.0f - wh) * wv;
    float w_lu = wh * (1.0f - wv);
    float w_ld = (1.0f - wh) * (1.0f - wv);

    int q = min(w0c, WW - 2);
    bool Ahi = (w0c != q);
    bool Bhi = (w1 == q + 1);
    float4 U = *reinterpret_cast<const float4*>(img + (size_t)(((h0c << 9) + q) << 2));
    float4 D = *reinterpret_cast<const float4*>(img + (size_t)(((h1  << 9) + q) << 2));
    float ru_ab = Ahi ? U.z : U.x, ru_c = Ahi ? U.w : U.y;
    float rd_ab = Ahi ? D.z : D.x, rd_c = Ahi ? D.w : D.y;
    float lu_ab = Bhi ? U.z : U.x, lu_c = Bhi ? U.w : U.y;
    float ld_ab = Bhi ? D.z : D.x, ld_c = Bhi ? D.w : D.y;

    float2 ruA = __half22float2(*reinterpret_cast<__half2*>(&ru_ab));
    float2 rdA = __half22float2(*reinterpret_cast<__half2*>(&rd_ab));
    float2 luA = __half22float2(*reinterpret_cast<__half2*>(&lu_ab));
    float2 ldA = __half22float2(*reinterpret_cast<__half2*>(&ld_ab));
    float ruZ = __half2float(reinterpret_cast<__half2*>(&ru_c)->x);
    float rdZ = __half2float(reinterpret_cast<__half2*>(&rd_c)->x);
    float luZ = __half2float(reinterpret_cast<__half2*>(&lu_c)->x);
    float ldZ = __half2float(reinterpret_cast<__half2*>(&ld_c)->x);

    out[0] = w_ru * ruA.x + w_rd * rdA.x + w_lu * luA.x + w_ld * ldA.x;
    out[1] = w_ru * ruA.y + w_rd * rdA.y + w_lu * luA.y + w_ld * ldA.y;
    out[2] = w_ru * ruZ   + w_rd * rdZ   + w_lu * luZ   + w_ld * ldZ;
}

__global__ __launch_bounds__(256, 4) void interp_tv_kernel(
    const __half* __restrict__ f0h, const __half* __restrict__ f1h,
    const float* __restrict__ flow, const float* __restrict__ mask,
    float* __restrict__ stacked, float* __restrict__ tv_out)
{
    int bid = blockIdx.x;                                  // 1024 blocks
    int wb  = (bid & 7) * (NPIX / 2048 / 8) + (bid >> 3);  // image n -> XCD n
    int idx0 = wb * 2048 + (int)threadIdx.x * 8;           // 8 adjacent px
    int w0 = idx0 & (WW - 1);
    int h  = (idx0 >> 9) & (HH - 1);
    int n  = idx0 >> 18;

    float4 fl[4];
#pragma unroll
    for (int j = 0; j < 4; ++j)
        fl[j] = *reinterpret_cast<const float4*>(flow + (size_t)idx0 * 2 + j * 4);
    float4 mkA = *reinterpret_cast<const float4*>(mask + idx0);
    float4 mkB = *reinterpret_cast<const float4*>(mask + idx0 + 4);
    const float* flp = reinterpret_cast<const float*>(fl);
    float mkp[8] = {mkA.x, mkA.y, mkA.z, mkA.w, mkB.x, mkB.y, mkB.z, mkB.w};

    float hhv = -1.0f + (float)h * (2.0f / 511.0f);

    const __half* i0 = f0h + (size_t)n * (HH * WW * 4);
    const __half* i1 = f1h + (size_t)n * (HH * WW * 4);

    float res[24];
#pragma unroll
    for (int p = 0; p < 8; ++p) {
        float wvx = -1.0f + (float)(w0 + p) * (2.0f / 511.0f);
        float fx = flp[p * 2], fy = flp[p * 2 + 1];
        float o0[3], o1[3];
        bilerp_h(i0, hhv + fx * 0.5f, wvx + fy * 0.5f, o0);
        bilerp_h(i1, hhv - fx * 0.5f, wvx - fy * 0.5f, o1);
        float m = 0.5f * (1.0f + mkp[p]), om = 1.0f - m;
#pragma unroll
        for (int c = 0; c < 3; ++c)
            res[p * 3 + c] = m * o0[c] + om * o1[c];
    }
    float4* sp = reinterpret_cast<float4*>(stacked + (size_t)idx0 * 3);
#pragma unroll
    for (int j = 0; j < 6; ++j)
        sp[j] = make_float4(res[j * 4], res[j * 4 + 1],
                            res[j * 4 + 2], res[j * 4 + 3]);

    float tvf = 0.0f, tvm = 0.0f;
#pragma unroll
    for (int p = 0; p < 7; ++p) {
        tvf += fabsf(flp[p * 2 + 2] - flp[p * 2])
             + fabsf(flp[p * 2 + 3] - flp[p * 2 + 1]);
        tvm += fabsf(mkp[p + 1] - mkp[p]);
    }
    if (w0 < WW - 8) {
        float2 flr = *reinterpret_cast<const float2*>(flow + (size_t)(idx0 + 8) * 2);
        float  mkr = mask[idx0 + 8];
        tvf += fabsf(flr.x - flp[14]) + fabsf(flr.y - flp[15]);
        tvm += fabsf(mkr - mkp[7]);
    }
    if (h < HH - 1) {
#pragma unroll
        for (int j = 0; j < 4; ++j) {
            float4 fd = *reinterpret_cast<const float4*>(
                            flow + (size_t)(idx0 + WW) * 2 + j * 4);
            tvf += fabsf(fd.x - flp[j * 4 + 0]) + fabsf(fd.y - flp[j * 4 + 1])
                 + fabsf(fd.z - flp[j * 4 + 2]) + fabsf(fd.w - flp[j * 4 + 3]);
        }
        float4 mdA = *reinterpret_cast<const float4*>(mask + idx0 + WW);
        float4 mdB = *reinterpret_cast<const float4*>(mask + idx0 + WW + 4);
        tvm += fabsf(mdA.x - mkp[0]) + fabsf(mdA.y - mkp[1])
             + fabsf(mdA.z - mkp[2]) + fabsf(mdA.w - mkp[3])
             + fabsf(mdB.x - mkp[4]) + fabsf(mdB.y - mkp[5])
             + fabsf(mdB.z - mkp[6]) + fabsf(mdB.w - mkp[7]);
    }
    float tv = GAMMA_FLOW * tvf + GAMMA_MASK * tvm;
#pragma unroll
    for (int off = 32; off > 0; off >>= 1) tv += __shfl_xor(tv, off);
    if ((threadIdx.x & 63) == 0) atomicAdd(tv_out, tv * INV_TOTAL);
}

extern "C" void kernel_launch(void* const* d_in, const int* in_sizes, int n_in,
                              void* d_out, int out_size, void* d_ws, size_t ws_size,
                              hipStream_t stream)
{
    const float* frames  = (const float*)d_in[0];
    const float* encoded = (const float*)d_in[1];
    const float* conv_w  = (const float*)d_in[2];
    const float* conv_b  = (const float*)d_in[3];

    float* out     = (float*)d_out;
    float* stacked = out;                       // NPIX*3
    float* flow    = out + (size_t)NPIX * 3;    // NPIX*2
    float* tv      = out + (size_t)NPIX * 5;    // 1

    const size_t frame_bytes = (size_t)NPIX * 4 * sizeof(__half); // 16 MiB each
    __half* f0h = (__half*)d_ws;
    __half* f1h = (__half*)((char*)d_ws + frame_bytes);
    float*  mask = (float*)((char*)d_ws + 2 * frame_bytes);

    fat_kernel<<<FAT_BLOCKS, 256, 0, stream>>>(
        encoded, conv_w, conv_b, frames, flow, mask, f0h, f1h, tv);
    interp_tv_kernel<<<NPIX / 2048, 256, 0, stream>>>(
        f0h, f1h, flow, mask, stacked, tv);
}

// Round 15
// 224.427 us; speedup vs baseline: 1.2785x; 1.1639x over previous
//
#include <hip/hip_runtime.h>
#include <hip/hip_fp16.h>
#include <math.h>

#define HH 512
#define WW 512
#define NIMG 8
#define NPIX (NIMG * HH * WW)          // 2,097,152
#define GAMMA_FLOW 0.001f
#define GAMMA_MASK 0.0005f
#define INV_TOTAL (1.0f / (float)(NPIX * 3))

#define CVT_BLOCKS  (NPIX / 256)       // 8192
#define CONV_BLOCKS (NPIX / 128)       // 16384
#define FAT_BLOCKS  (CVT_BLOCKS + CONV_BLOCKS)  // 24576

__device__ __forceinline__ float tanh_fast(float x)
{
    float e = __expf(2.0f * x);
    return 1.0f - 2.0f / (e + 1.0f);
}

__device__ __forceinline__ void fma12(float acc[3], const float wf[12],
                                      float4 x)
{
    float xv[4] = {x.x, x.y, x.z, x.w};
#pragma unroll
    for (int k = 0; k < 4; ++k) {
        acc[0] = fmaf(xv[k], wf[k * 3 + 0], acc[0]);
        acc[1] = fmaf(xv[k], wf[k * 3 + 1], acc[1]);
        acc[2] = fmaf(xv[k], wf[k * 3 + 2], acc[2]);
    }
}

// ========== K1 (fat): bid%3==0 -> cvt block ; else -> conv block ============
// Conv v2: 4 ADJACENT px/thread with a 6-wide register window slid across kw
// -> 18 enc loads/thread (was 36 with the strided-px layout), same 432 FMA.
// Conv is L1/L2-latency bound on load count (FETCH 162MB < 268MB compulsory
// -> caches fine; occupancy pinned at 4 w/EU by the 64-reg budget law).
// Reg estimate: win 24 + wf 12 + acc 12 + addr ~ 60 <= 64 proven budget.
__global__ __launch_bounds__(256, 4) void fat_kernel(
    const float* __restrict__ enc, const float* __restrict__ cw,
    const float* __restrict__ cb, const float* __restrict__ frames,
    float* __restrict__ flow, float* __restrict__ mask,
    __half* __restrict__ f0h, __half* __restrict__ f1h,
    float* __restrict__ tv_out)
{
    int bid = blockIdx.x;

    if (bid % 3 == 0) {
        // ---------------- cvt: fp32 NHWC(6) -> two planar fp16(4) ----------
        int ci = bid / 3;                              // 0..8191
        int t  = ci * 256 + threadIdx.x;               // one pixel
        if (t == 0) tv_out[0] = 0.0f;
        const float2* fp = reinterpret_cast<const float2*>(frames + (size_t)t * 6);
        float2 v0 = fp[0], v1 = fp[1], v2 = fp[2];
        __half2 a = __floats2half2_rn(v0.x, v0.y);
        __half2 b = __floats2half2_rn(v1.x, 0.0f);
        __half2 c = __floats2half2_rn(v1.y, v2.x);
        __half2 d = __floats2half2_rn(v2.y, 0.0f);
        __half2* p0 = reinterpret_cast<__half2*>(f0h) + (size_t)t * 2;
        __half2* p1 = reinterpret_cast<__half2*>(f1h) + (size_t)t * 2;
        p0[0] = a; p0[1] = b;
        p1[0] = c; p1[1] = d;
        return;
    }

    // ---------------- conv: 3x3x32->3 + tanh, sliding window ---------------
    int ci  = bid - (bid + 2) / 3;                        // 0..16383
    int wb  = (ci & 7) * (CONV_BLOCKS / 8) + (ci >> 3);   // image n -> XCD n
    int px0 = wb * 128;
    int n = px0 >> 18;
    int h = (px0 >> 9) & (HH - 1);

    int tid  = threadIdx.x;
    int wv   = tid >> 6;
    int lane = tid & 63;
    int pg   = lane >> 3;                                 // pixel group (0..7)
    int c4   = lane & 7;                                  // channel chunk

    int wbase = (px0 & (WW - 1)) + wv * 32;               // wave's 32-px seg
    int pxb   = wbase + pg * 4;                           // thread's 4 px base

    const float4* cwB = reinterpret_cast<const float4*>(cw) + c4 * 3;
    const float* imgbase = enc + ((size_t)n * HH) * (WW * 32);

    float acc[4][3];
#pragma unroll
    for (int p = 0; p < 4; ++p)
        acc[p][0] = acc[p][1] = acc[p][2] = 0.0f;

    bool edge = (wbase == 0) || (wbase == WW - 32);       // wave-uniform

#pragma unroll
    for (int kh = 0; kh < 3; ++kh) {
        int hr = h + kh - 1;
        if ((unsigned)hr >= (unsigned)HH) continue;       // block-uniform
        const float* rowp = imgbase + (size_t)hr * (WW * 32);

        float4 win[6];                                    // cols pxb-1..pxb+4
        if (!edge) {
            const float* pB = rowp + (pxb - 1) * 32 + c4 * 4;
#pragma unroll
            for (int j = 0; j < 6; ++j)
                win[j] = *reinterpret_cast<const float4*>(pB + j * 32);
        } else {
#pragma unroll
            for (int j = 0; j < 6; ++j) {
                int col = pxb + j - 1;
                win[j] = make_float4(0.f, 0.f, 0.f, 0.f);
                if ((unsigned)col < (unsigned)WW)
                    win[j] = *reinterpret_cast<const float4*>(
                                 rowp + (size_t)col * 32 + c4 * 4);
            }
        }

#pragma unroll
        for (int kw = 0; kw < 3; ++kw) {
            int t = kh * 3 + kw;
            float wf[12];
            *reinterpret_cast<float4*>(&wf[0]) = cwB[t * 24 + 0];
            *reinterpret_cast<float4*>(&wf[4]) = cwB[t * 24 + 1];
            *reinterpret_cast<float4*>(&wf[8]) = cwB[t * 24 + 2];
#pragma unroll
            for (int p = 0; p < 4; ++p)
                fma12(acc[p], wf, win[p + kw]);
        }
    }

    float b0 = cb[0], b1 = cb[1], b2 = cb[2];
    size_t rowidx = ((size_t)n * HH + h) * WW;

#pragma unroll
    for (int p = 0; p < 4; ++p) {
#pragma unroll
        for (int off = 1; off < 8; off <<= 1) {           // reduce over c4
            acc[p][0] += __shfl_xor(acc[p][0], off);
            acc[p][1] += __shfl_xor(acc[p][1], off);
            acc[p][2] += __shfl_xor(acc[p][2], off);
        }
    }
    if (c4 == 0) {
#pragma unroll
        for (int p = 0; p < 4; ++p) {
            size_t idx = rowidx + (size_t)(pxb + p);
            *reinterpret_cast<float2*>(flow + idx * 2) =
                make_float2(tanh_fast(acc[p][0] + b0),
                            tanh_fast(acc[p][1] + b1));
            mask[idx] = tanh_fast(acc[p][2] + b2);
        }
    }
}

// ================= K2: bilinear warp + blend + TV (unchanged, ~47us) ========
__device__ __forceinline__ void bilerp_h(const __half* __restrict__ img,
                                         float ch, float cwv, float out[3])
{
    float hp = (ch + 1.0f) * 255.5f;
    float wp = (cwv + 1.0f) * 255.5f;
    int h0 = (int)floorf(hp);
    int w0 = (int)floorf(wp);
    int h1  = min(max(h0 + 1, 0), HH - 1);
    int w1  = min(max(w0 + 1, 0), WW - 1);
    int h0c = min(max(h0, 0), HH - 1);
    int w0c = min(max(w0, 0), WW - 1);
    float wh = (float)h1 - hp;
    float wv = (float)w1 - wp;
    float w_ru = wh * wv;
    float w_rd = (1.0f - wh) * wv;
    float w_lu = wh * (1.0f - wv);
    float w_ld = (1.0f - wh) * (1.0f - wv);

    int q = min(w0c, WW - 2);
    bool Ahi = (w0c != q);
    bool Bhi = (w1 == q + 1);
    float4 U = *reinterpret_cast<const float4*>(img + (size_t)(((h0c << 9) + q) << 2));
    float4 D = *reinterpret_cast<const float4*>(img + (size_t)(((h1  << 9) + q) << 2));
    float ru_ab = Ahi ? U.z : U.x, ru_c = Ahi ? U.w : U.y;
    float rd_ab = Ahi ? D.z : D.x, rd_c = Ahi ? D.w : D.y;
    float lu_ab = Bhi ? U.z : U.x, lu_c = Bhi ? U.w : U.y;
    float ld_ab = Bhi ? D.z : D.x, ld_c = Bhi ? D.w : D.y;

    float2 ruA = __half22float2(*reinterpret_cast<__half2*>(&ru_ab));
    float2 rdA = __half22float2(*reinterpret_cast<__half2*>(&rd_ab));
    float2 luA = __half22float2(*reinterpret_cast<__half2*>(&lu_ab));
    float2 ldA = __half22float2(*reinterpret_cast<__half2*>(&ld_ab));
    float ruZ = __half2float(reinterpret_cast<__half2*>(&ru_c)->x);
    float rdZ = __half2float(reinterpret_cast<__half2*>(&rd_c)->x);
    float luZ = __half2float(reinterpret_cast<__half2*>(&lu_c)->x);
    float ldZ = __half2float(reinterpret_cast<__half2*>(&ld_c)->x);

    out[0] = w_ru * ruA.x + w_rd * rdA.x + w_lu * luA.x + w_ld * ldA.x;
    out[1] = w_ru * ruA.y + w_rd * rdA.y + w_lu * luA.y + w_ld * ldA.y;
    out[2] = w_ru * ruZ   + w_rd * rdZ   + w_lu * luZ   + w_ld * ldZ;
}

__global__ __launch_bounds__(256, 4) void interp_tv_kernel(
    const __half* __restrict__ f0h, const __half* __restrict__ f1h,
    const float* __restrict__ flow, const float* __restrict__ mask,
    float* __restrict__ stacked, float* __restrict__ tv_out)
{
    int bid = blockIdx.x;                                  // 1024 blocks
    int wb  = (bid & 7) * (NPIX / 2048 / 8) + (bid >> 3);  // image n -> XCD n
    int idx0 = wb * 2048 + (int)threadIdx.x * 8;           // 8 adjacent px
    int w0 = idx0 & (WW - 1);
    int h  = (idx0 >> 9) & (HH - 1);
    int n  = idx0 >> 18;

    float4 fl[4];
#pragma unroll
    for (int j = 0; j < 4; ++j)
        fl[j] = *reinterpret_cast<const float4*>(flow + (size_t)idx0 * 2 + j * 4);
    float4 mkA = *reinterpret_cast<const float4*>(mask + idx0);
    float4 mkB = *reinterpret_cast<const float4*>(mask + idx0 + 4);
    const float* flp = reinterpret_cast<const float*>(fl);
    float mkp[8] = {mkA.x, mkA.y, mkA.z, mkA.w, mkB.x, mkB.y, mkB.z, mkB.w};

    float hhv = -1.0f + (float)h * (2.0f / 511.0f);

    const __half* i0 = f0h + (size_t)n * (HH * WW * 4);
    const __half* i1 = f1h + (size_t)n * (HH * WW * 4);

    float res[24];
#pragma unroll
    for (int p = 0; p < 8; ++p) {
        float wvx = -1.0f + (float)(w0 + p) * (2.0f / 511.0f);
        float fx = flp[p * 2], fy = flp[p * 2 + 1];
        float o0[3], o1[3];
        bilerp_h(i0, hhv + fx * 0.5f, wvx + fy * 0.5f, o0);
        bilerp_h(i1, hhv - fx * 0.5f, wvx - fy * 0.5f, o1);
        float m = 0.5f * (1.0f + mkp[p]), om = 1.0f - m;
#pragma unroll
        for (int c = 0; c < 3; ++c)
            res[p * 3 + c] = m * o0[c] + om * o1[c];
    }
    float4* sp = reinterpret_cast<float4*>(stacked + (size_t)idx0 * 3);
#pragma unroll
    for (int j = 0; j < 6; ++j)
        sp[j] = make_float4(res[j * 4], res[j * 4 + 1],
                            res[j * 4 + 2], res[j * 4 + 3]);

    float tvf = 0.0f, tvm = 0.0f;
#pragma unroll
    for (int p = 0; p < 7; ++p) {
        tvf += fabsf(flp[p * 2 + 2] - flp[p * 2])
             + fabsf(flp[p * 2 + 3] - flp[p * 2 + 1]);
        tvm += fabsf(mkp[p + 1] - mkp[p]);
    }
    if (w0 < WW - 8) {
        float2 flr = *reinterpret_cast<const float2*>(flow + (size_t)(idx0 + 8) * 2);
        float  mkr = mask[idx0 + 8];
        tvf += fabsf(flr.x - flp[14]) + fabsf(flr.y - flp[15]);
        tvm += fabsf(mkr - mkp[7]);
    }
    if (h < HH - 1) {
#pragma unroll
        for (int j = 0; j < 4; ++j) {
            float4 fd = *reinterpret_cast<const float4*>(
                            flow + (size_t)(idx0 + WW) * 2 + j * 4);
            tvf += fabsf(fd.x - flp[j * 4 + 0]) + fabsf(fd.y - flp[j * 4 + 1])
                 + fabsf(fd.z - flp[j * 4 + 2]) + fabsf(fd.w - flp[j * 4 + 3]);
        }
        float4 mdA = *reinterpret_cast<const float4*>(mask + idx0 + WW);
        float4 mdB = *reinterpret_cast<const float4*>(mask + idx0 + WW + 4);
        tvm += fabsf(mdA.x - mkp[0]) + fabsf(mdA.y - mkp[1])
             + fabsf(mdA.z - mkp[2]) + fabsf(mdA.w - mkp[3])
             + fabsf(mdB.x - mkp[4]) + fabsf(mdB.y - mkp[5])
             + fabsf(mdB.z - mkp[6]) + fabsf(mdB.w - mkp[7]);
    }
    float tv = GAMMA_FLOW * tvf + GAMMA_MASK * tvm;
#pragma unroll
    for (int off = 32; off > 0; off >>= 1) tv += __shfl_xor(tv, off);
    if ((threadIdx.x & 63) == 0) atomicAdd(tv_out, tv * INV_TOTAL);
}

extern "C" void kernel_launch(void* const* d_in, const int* in_sizes, int n_in,
                              void* d_out, int out_size, void* d_ws, size_t ws_size,
                              hipStream_t stream)
{
    const float* frames  = (const float*)d_in[0];
    const float* encoded = (const float*)d_in[1];
    const float* conv_w  = (const float*)d_in[2];
    const float* conv_b  = (const float*)d_in[3];

    float* out     = (float*)d_out;
    float* stacked = out;                       // NPIX*3
    float* flow    = out + (size_t)NPIX * 3;    // NPIX*2
    float* tv      = out + (size_t)NPIX * 5;    // 1

    const size_t frame_bytes = (size_t)NPIX * 4 * sizeof(__half); // 16 MiB each
    __half* f0h = (__half*)d_ws;
    __half* f1h = (__half*)((char*)d_ws + frame_bytes);
    float*  mask = (float*)((char*)d_ws + 2 * frame_bytes);

    fat_kernel<<<FAT_BLOCKS, 256, 0, stream>>>(
        encoded, conv_w, conv_b, frames, flow, mask, f0h, f1h, tv);
    interp_tv_kernel<<<NPIX / 2048, 256, 0, stream>>>(
        f0h, f1h, flow, mask, stacked, tv);
}